// Round 1
// baseline (1304.637 us; speedup 1.0000x reference)
//
#include <hip/hip_runtime.h>

// LightGCN: N = U + I nodes, E undirected edges -> 2E directed CSR entries.
// Pipeline per call (everything rebuilt each call; ws is re-poisoned):
//   memset(degf,degc,counter) -> k_degree -> k_offsets(scan) -> k_scatter
//   -> k_initemb -> 4x k_layer (ping-pong) -> k_final

static inline size_t align_up(size_t x, size_t a) { return (x + a - 1) & ~(a - 1); }

__global__ void k_degree(const int* __restrict__ eu, const int* __restrict__ ei,
                         const float* __restrict__ ev,
                         float* __restrict__ degf, int* __restrict__ degc,
                         int U, int E) {
    int e = blockIdx.x * blockDim.x + threadIdx.x;
    if (e >= E) return;
    int u = eu[e];
    int it = ei[e] + U;
    float v = ev[e];
    atomicAdd(&degf[u], v);
    atomicAdd(&degf[it], v);
    atomicAdd(&degc[u], 1);
    atomicAdd(&degc[it], 1);
}

// Block-level inclusive scan of degc + one global atomic per block to get
// disjoint CSR offset ranges. Also computes dinv = rsqrt(deg) (0 if deg==0).
__global__ __launch_bounds__(256) void k_offsets(
        const float* __restrict__ degf, const int* __restrict__ degc,
        float* __restrict__ dinv, int* __restrict__ offs,
        int* __restrict__ cursor, int* __restrict__ counter, int N) {
    __shared__ int sdata[256];
    __shared__ int sbase;
    int t = threadIdx.x;
    int n = blockIdx.x * 256 + t;
    int c = (n < N) ? degc[n] : 0;
    sdata[t] = c;
    __syncthreads();
    // Hillis-Steele inclusive scan
    for (int d = 1; d < 256; d <<= 1) {
        int v = (t >= d) ? sdata[t - d] : 0;
        __syncthreads();
        sdata[t] += v;
        __syncthreads();
    }
    if (t == 255) sbase = atomicAdd(counter, sdata[255]);
    __syncthreads();
    if (n < N) {
        int o = sbase + sdata[t] - c;   // exclusive scan + block base
        offs[n] = o;
        cursor[n] = o;
        float dg = degf[n];
        dinv[n] = (dg > 0.0f) ? rsqrtf(fmaxf(dg, 1e-12f)) : 0.0f;
    }
}

// Scatter both directions of each edge into CSR as packed {col, weight}.
__global__ void k_scatter(const int* __restrict__ eu, const int* __restrict__ ei,
                          const float* __restrict__ ev, const float* __restrict__ dinv,
                          int* __restrict__ cursor, int2* __restrict__ csr,
                          int U, int E) {
    int e = blockIdx.x * blockDim.x + threadIdx.x;
    if (e >= E) return;
    int u = eu[e];
    int it = ei[e] + U;
    float w = ev[e] * dinv[u] * dinv[it];
    int2 a;
    a.y = __float_as_int(w);
    a.x = it;
    int p = atomicAdd(&cursor[u], 1);
    csr[p] = a;
    a.x = u;
    int p2 = atomicAdd(&cursor[it], 1);
    csr[p2] = a;
}

// e0 = concat(emb_users, emb_items); acc = e0. float4-vectorized.
__global__ void k_initemb(const float4* __restrict__ emb_u, const float4* __restrict__ emb_i,
                          float4* __restrict__ e0, float4* __restrict__ acc,
                          int U16, int N16) {
    int i = blockIdx.x * blockDim.x + threadIdx.x;
    if (i >= N16) return;
    float4 v = (i < U16) ? emb_u[i] : emb_i[i - U16];
    e0[i] = v;
    acc[i] = v;
}

// One wave (64 lanes) per node; lane = embedding dim.
// Lanes cooperatively load up to 64 CSR entries (coalesced), then broadcast
// each entry via __shfl and gather e[c*64+lane] (coalesced 256B/neighbor).
// 4 accumulators for memory-level parallelism.
__global__ __launch_bounds__(256) void k_layer(
        const float* __restrict__ ein, float* __restrict__ eout,
        float* __restrict__ acc,
        const int* __restrict__ offs, const int* __restrict__ degc,
        const int2* __restrict__ csr, int N) {
    int gtid = blockIdx.x * blockDim.x + threadIdx.x;
    int wid = gtid >> 6;          // node id (uniform across the wave)
    int lane = threadIdx.x & 63;  // dim
    if (wid >= N) return;
    int base = offs[wid];
    int cnt = degc[wid];
    float s0 = 0.f, s1 = 0.f, s2 = 0.f, s3 = 0.f;
    for (int k0 = 0; k0 < cnt; k0 += 64) {
        int idx = k0 + lane;
        int2 cw = make_int2(0, 0);
        if (idx < cnt) cw = csr[base + idx];
        int m = min(cnt - k0, 64);
        int j = 0;
        for (; j + 4 <= m; j += 4) {
            int   c0 = __shfl(cw.x, j);
            int   c1 = __shfl(cw.x, j + 1);
            int   c2 = __shfl(cw.x, j + 2);
            int   c3 = __shfl(cw.x, j + 3);
            float w0 = __int_as_float(__shfl(cw.y, j));
            float w1 = __int_as_float(__shfl(cw.y, j + 1));
            float w2 = __int_as_float(__shfl(cw.y, j + 2));
            float w3 = __int_as_float(__shfl(cw.y, j + 3));
            s0 += w0 * ein[c0 * 64 + lane];
            s1 += w1 * ein[c1 * 64 + lane];
            s2 += w2 * ein[c2 * 64 + lane];
            s3 += w3 * ein[c3 * 64 + lane];
        }
        for (; j < m; ++j) {
            int   c = __shfl(cw.x, j);
            float w = __int_as_float(__shfl(cw.y, j));
            s0 += w * ein[c * 64 + lane];
        }
    }
    float sum = (s0 + s1) + (s2 + s3);
    int o = wid * 64 + lane;
    eout[o] = sum;
    acc[o] += sum;
}

// out layout (float4 units): [Uf (U16) | Upass (U16) | If (I16) | Ipass (I16)]
__global__ void k_final(const float4* __restrict__ acc,
                        const float4* __restrict__ emb_u, const float4* __restrict__ emb_i,
                        float4* __restrict__ out, int U16, int I16) {
    int i = blockIdx.x * blockDim.x + threadIdx.x;
    int total = 2 * U16 + 2 * I16;
    if (i >= total) return;
    const float s = 1.0f / 25.0f;  // alpha * 1/(L+1) = 1/5 * 1/5
    float4 r;
    if (i < U16) {
        float4 a = acc[i];
        r = make_float4(a.x * s, a.y * s, a.z * s, a.w * s);
    } else if (i < 2 * U16) {
        r = emb_u[i - U16];
    } else if (i < 2 * U16 + I16) {
        float4 a = acc[U16 + (i - 2 * U16)];
        r = make_float4(a.x * s, a.y * s, a.z * s, a.w * s);
    } else {
        r = emb_i[i - 2 * U16 - I16];
    }
    out[i] = r;
}

extern "C" void kernel_launch(void* const* d_in, const int* in_sizes, int n_in,
                              void* d_out, int out_size, void* d_ws, size_t ws_size,
                              hipStream_t stream) {
    const float* emb_u = (const float*)d_in[0];
    const float* emb_i = (const float*)d_in[1];
    const int*   eu    = (const int*)d_in[2];
    const int*   ei    = (const int*)d_in[3];
    const float* ev    = (const float*)d_in[4];

    const int U = in_sizes[0] / 64;
    const int I = in_sizes[1] / 64;
    const int N = U + I;
    const int E = in_sizes[2];
    const int DE = 2 * E;  // directed edges

    // ---- workspace carve (degf, degc, counter contiguous for single memset) ----
    char* base = (char*)d_ws;
    size_t off = 0;
    float* degf = (float*)(base + off); off = align_up(off + (size_t)N * 4, 256);
    int*   degc = (int*)  (base + off); off = align_up(off + (size_t)N * 4, 256);
    int*   counter = (int*)(base + off); off = align_up(off + 256, 256);
    size_t zero_span = off;  // [0, off) must be zeroed
    float* dinv   = (float*)(base + off); off = align_up(off + (size_t)N * 4, 256);
    int*   offs   = (int*)  (base + off); off = align_up(off + (size_t)N * 4, 256);
    int*   cursor = (int*)  (base + off); off = align_up(off + (size_t)N * 4, 256);
    int2*  csr    = (int2*) (base + off); off = align_up(off + (size_t)DE * 8, 256);
    float* e0     = (float*)(base + off); off = align_up(off + (size_t)N * 64 * 4, 256);
    float* e1     = (float*)(base + off); off = align_up(off + (size_t)N * 64 * 4, 256);
    float* acc    = (float*)(base + off); off = align_up(off + (size_t)N * 64 * 4, 256);
    (void)ws_size;

    hipMemsetAsync(d_ws, 0, zero_span, stream);

    const int B = 256;
    k_degree<<<(E + B - 1) / B, B, 0, stream>>>(eu, ei, ev, degf, degc, U, E);
    k_offsets<<<(N + B - 1) / B, B, 0, stream>>>(degf, degc, dinv, offs, cursor, counter, N);
    k_scatter<<<(E + B - 1) / B, B, 0, stream>>>(eu, ei, ev, dinv, cursor, csr, U, E);

    const int U16 = U * 16, I16 = I * 16, N16 = N * 16;
    k_initemb<<<(N16 + B - 1) / B, B, 0, stream>>>((const float4*)emb_u, (const float4*)emb_i,
                                                   (float4*)e0, (float4*)acc, U16, N16);

    float* bufs[2] = {e0, e1};
    int p = 0;
    for (int layer = 0; layer < 4; ++layer) {
        int threads = N * 64;
        k_layer<<<(threads + B - 1) / B, B, 0, stream>>>(bufs[p], bufs[1 - p], acc,
                                                         offs, degc, csr, N);
        p ^= 1;
    }

    int totalv4 = 2 * U16 + 2 * I16;
    k_final<<<(totalv4 + B - 1) / B, B, 0, stream>>>((const float4*)acc,
                                                     (const float4*)emb_u, (const float4*)emb_i,
                                                     (float4*)d_out, U16, I16);
}

// Round 2
// 995.370 us; speedup vs baseline: 1.3107x; 1.3107x over previous
//
#include <hip/hip_runtime.h>

// LightGCN, atomic-minimized pipeline (2 atomics per undirected edge total):
//   memset(cnt,counter) -> k_count (atomic tickets) -> k_offsets (scan)
//   -> k_scatter (plain stores, slot = offs+ticket) -> k_dinv (wave reduce)
//   -> k_init (g0 = dinv*e0, acc = e0) -> 4x k_layer (g-form propagation)
//   -> k_final
//
// g-form: with g = dinv (*) e,  s_r = sum_{c in N(r)} v * g_c,
//   e'_r = dinv_r * s_r  (added to acc),  g'_r = dinv_r * e'_r.
// Identical math to e' = D^-1/2 A D^-1/2 e, but needs only the wave-uniform
// dinv[row], never dinv[col] per edge.

static inline size_t align_up(size_t x, size_t a) { return (x + a - 1) & ~(a - 1); }

// 2 atomics/edge; tickets (return values) make the scatter pass atomic-free.
__global__ void k_count(const int* __restrict__ eu, const int* __restrict__ ei,
                        int* __restrict__ cnt,
                        int* __restrict__ tick_u, int* __restrict__ tick_i,
                        int U, int E) {
    int e = blockIdx.x * blockDim.x + threadIdx.x;
    if (e >= E) return;
    int u = eu[e];
    int it = ei[e] + U;
    tick_u[e] = atomicAdd(&cnt[u], 1);
    tick_i[e] = atomicAdd(&cnt[it], 1);
}

// Block-level inclusive scan of cnt + one global atomic per block -> disjoint
// CSR offset ranges (row order across blocks is non-deterministic but rows are
// disjoint and correctly sized, which is all we need).
__global__ __launch_bounds__(256) void k_offsets(
        const int* __restrict__ cnt, int* __restrict__ offs,
        int* __restrict__ counter, int N) {
    __shared__ int sdata[256];
    __shared__ int sbase;
    int t = threadIdx.x;
    int n = blockIdx.x * 256 + t;
    int c = (n < N) ? cnt[n] : 0;
    sdata[t] = c;
    __syncthreads();
    for (int d = 1; d < 256; d <<= 1) {
        int v = (t >= d) ? sdata[t - d] : 0;
        __syncthreads();
        sdata[t] += v;
        __syncthreads();
    }
    if (t == 255) sbase = atomicAdd(counter, sdata[255]);
    __syncthreads();
    if (n < N) offs[n] = sbase + sdata[t] - c;   // exclusive scan + block base
}

// Atomic-free scatter: slot = offs[node] + ticket. Stores {col, raw v}.
__global__ void k_scatter(const int* __restrict__ eu, const int* __restrict__ ei,
                          const float* __restrict__ ev,
                          const int* __restrict__ offs,
                          const int* __restrict__ tick_u, const int* __restrict__ tick_i,
                          int2* __restrict__ csr, int U, int E) {
    int e = blockIdx.x * blockDim.x + threadIdx.x;
    if (e >= E) return;
    int u = eu[e];
    int it = ei[e] + U;
    int vy = __float_as_int(ev[e]);
    int2 a;
    a.x = it; a.y = vy;
    csr[offs[u] + tick_u[e]] = a;
    a.x = u;
    csr[offs[it] + tick_i[e]] = a;
}

// One wave per node: deg = sum of v over the CSR row (coalesced), dinv=rsqrt.
__global__ __launch_bounds__(256) void k_dinv(
        const int2* __restrict__ csr, const int* __restrict__ offs,
        const int* __restrict__ cnt, float* __restrict__ dinv, int N) {
    int gtid = blockIdx.x * blockDim.x + threadIdx.x;
    int wid = gtid >> 6;
    int lane = threadIdx.x & 63;
    if (wid >= N) return;
    int base = offs[wid];
    int c = cnt[wid];
    float s = 0.f;
    for (int k = lane; k < c; k += 64) s += __int_as_float(csr[base + k].y);
    #pragma unroll
    for (int d = 32; d > 0; d >>= 1) s += __shfl_down(s, d);
    if (lane == 0) dinv[wid] = (s > 0.0f) ? rsqrtf(fmaxf(s, 1e-12f)) : 0.0f;
}

// g0 = dinv * concat(emb); acc = concat(emb). float4-vectorized (4 dims/thread).
__global__ void k_init(const float4* __restrict__ emb_u, const float4* __restrict__ emb_i,
                       const float* __restrict__ dinv,
                       float4* __restrict__ g0, float4* __restrict__ acc,
                       int U16, int N16) {
    int i = blockIdx.x * blockDim.x + threadIdx.x;
    if (i >= N16) return;
    float4 v = (i < U16) ? emb_u[i] : emb_i[i - U16];
    acc[i] = v;
    float d = dinv[i >> 4];
    g0[i] = make_float4(v.x * d, v.y * d, v.z * d, v.w * d);
}

// One wave per node; lane = dim. Lanes cooperatively load 64 CSR entries
// (coalesced), shfl-broadcast, gather g[c*64+lane] (coalesced 256B/neighbor).
__global__ __launch_bounds__(256) void k_layer(
        const float* __restrict__ gin, float* __restrict__ gout,
        float* __restrict__ acc, const float* __restrict__ dinv,
        const int* __restrict__ offs, const int* __restrict__ cnt,
        const int2* __restrict__ csr, int N, int write_g) {
    int gtid = blockIdx.x * blockDim.x + threadIdx.x;
    int wid = gtid >> 6;
    int lane = threadIdx.x & 63;
    if (wid >= N) return;
    int base = offs[wid];
    int c = cnt[wid];
    float s0 = 0.f, s1 = 0.f, s2 = 0.f, s3 = 0.f;
    for (int k0 = 0; k0 < c; k0 += 64) {
        int idx = k0 + lane;
        int2 cw = make_int2(0, 0);
        if (idx < c) cw = csr[base + idx];
        int m = min(c - k0, 64);
        int j = 0;
        for (; j + 4 <= m; j += 4) {
            int   c0 = __shfl(cw.x, j);
            int   c1 = __shfl(cw.x, j + 1);
            int   c2 = __shfl(cw.x, j + 2);
            int   c3 = __shfl(cw.x, j + 3);
            float w0 = __int_as_float(__shfl(cw.y, j));
            float w1 = __int_as_float(__shfl(cw.y, j + 1));
            float w2 = __int_as_float(__shfl(cw.y, j + 2));
            float w3 = __int_as_float(__shfl(cw.y, j + 3));
            s0 += w0 * gin[c0 * 64 + lane];
            s1 += w1 * gin[c1 * 64 + lane];
            s2 += w2 * gin[c2 * 64 + lane];
            s3 += w3 * gin[c3 * 64 + lane];
        }
        for (; j < m; ++j) {
            int   cc = __shfl(cw.x, j);
            float w  = __int_as_float(__shfl(cw.y, j));
            s0 += w * gin[cc * 64 + lane];
        }
    }
    float dr = dinv[wid];
    float ep = dr * ((s0 + s1) + (s2 + s3));   // e'_r
    int o = wid * 64 + lane;
    acc[o] += ep;
    if (write_g) gout[o] = dr * ep;            // g'_r = dinv^2 * s
}

// out layout (float4 units): [Uf | Upass | If | Ipass]
__global__ void k_final(const float4* __restrict__ acc,
                        const float4* __restrict__ emb_u, const float4* __restrict__ emb_i,
                        float4* __restrict__ out, int U16, int I16) {
    int i = blockIdx.x * blockDim.x + threadIdx.x;
    int total = 2 * U16 + 2 * I16;
    if (i >= total) return;
    const float s = 1.0f / 25.0f;  // alpha * 1/(L+1) = 1/5 * 1/5
    float4 r;
    if (i < U16) {
        float4 a = acc[i];
        r = make_float4(a.x * s, a.y * s, a.z * s, a.w * s);
    } else if (i < 2 * U16) {
        r = emb_u[i - U16];
    } else if (i < 2 * U16 + I16) {
        float4 a = acc[U16 + (i - 2 * U16)];
        r = make_float4(a.x * s, a.y * s, a.z * s, a.w * s);
    } else {
        r = emb_i[i - 2 * U16 - I16];
    }
    out[i] = r;
}

extern "C" void kernel_launch(void* const* d_in, const int* in_sizes, int n_in,
                              void* d_out, int out_size, void* d_ws, size_t ws_size,
                              hipStream_t stream) {
    const float* emb_u = (const float*)d_in[0];
    const float* emb_i = (const float*)d_in[1];
    const int*   eu    = (const int*)d_in[2];
    const int*   ei    = (const int*)d_in[3];
    const float* ev    = (const float*)d_in[4];

    const int U = in_sizes[0] / 64;
    const int I = in_sizes[1] / 64;
    const int N = U + I;
    const int E = in_sizes[2];
    const int DE = 2 * E;

    // ---- workspace carve (cnt+counter first: single small memset) ----
    char* base = (char*)d_ws;
    size_t off = 0;
    int*   cnt     = (int*)(base + off); off = align_up(off + (size_t)N * 4, 256);
    int*   counter = (int*)(base + off); off = align_up(off + 256, 256);
    size_t zero_span = off;
    int*   offs   = (int*)  (base + off); off = align_up(off + (size_t)N * 4, 256);
    float* dinv   = (float*)(base + off); off = align_up(off + (size_t)N * 4, 256);
    int*   tick_u = (int*)  (base + off); off = align_up(off + (size_t)E * 4, 256);
    int*   tick_i = (int*)  (base + off); off = align_up(off + (size_t)E * 4, 256);
    int2*  csr    = (int2*) (base + off); off = align_up(off + (size_t)DE * 8, 256);
    float* g0     = (float*)(base + off); off = align_up(off + (size_t)N * 64 * 4, 256);
    float* g1     = (float*)(base + off); off = align_up(off + (size_t)N * 64 * 4, 256);
    float* acc    = (float*)(base + off); off = align_up(off + (size_t)N * 64 * 4, 256);
    (void)ws_size;

    hipMemsetAsync(d_ws, 0, zero_span, stream);

    const int B = 256;
    k_count<<<(E + B - 1) / B, B, 0, stream>>>(eu, ei, cnt, tick_u, tick_i, U, E);
    k_offsets<<<(N + B - 1) / B, B, 0, stream>>>(cnt, offs, counter, N);
    k_scatter<<<(E + B - 1) / B, B, 0, stream>>>(eu, ei, ev, offs, tick_u, tick_i, csr, U, E);
    k_dinv<<<(N * 64 + B - 1) / B, B, 0, stream>>>(csr, offs, cnt, dinv, N);

    const int U16 = U * 16, I16 = I * 16, N16 = N * 16;
    k_init<<<(N16 + B - 1) / B, B, 0, stream>>>((const float4*)emb_u, (const float4*)emb_i,
                                                dinv, (float4*)g0, (float4*)acc, U16, N16);

    float* bufs[2] = {g0, g1};
    int p = 0;
    for (int layer = 0; layer < 4; ++layer) {
        int threads = N * 64;
        k_layer<<<(threads + B - 1) / B, B, 0, stream>>>(bufs[p], bufs[1 - p], acc, dinv,
                                                         offs, cnt, csr, N,
                                                         layer < 3 ? 1 : 0);
        p ^= 1;
    }

    int totalv4 = 2 * U16 + 2 * I16;
    k_final<<<(totalv4 + B - 1) / B, B, 0, stream>>>((const float4*)acc,
                                                     (const float4*)emb_u, (const float4*)emb_i,
                                                     (float4*)d_out, U16, I16);
}

// Round 3
// 866.336 us; speedup vs baseline: 1.5059x; 1.1489x over previous
//
#include <hip/hip_runtime.h>

// LightGCN, atomic-minimized + bf16 g-form propagation.
// Pipeline: memset(cnt,counter) -> k_count (2 atomics/edge, tickets)
//   -> k_offsets (block scan) -> k_scatter (atomic-free) -> k_dinv
//   -> k_init (g0 = bf16(dinv*e0)) -> 4x k_layer (g_l -> g_{l+1}, bf16)
//   -> k_final (out = (e0 + sum_l dsq*g_l)/25, + passthroughs)
//
// g-form: g = dinv (*) e;  s_r = sum v*g_c;  e'_r = dinv_r*s_r;  g' = dinv_r*e'_r.
// Final reconstructs e_l = dsq * g_l (dsq = sqrt(deg), 0 when deg==0), so
// layers never touch a fp32 accumulator (saves 4x77MB RMW).

static inline size_t align_up(size_t x, size_t a) { return (x + a - 1) & ~(a - 1); }

__device__ inline unsigned short f32_to_bf16(float f) {
    unsigned int u = __float_as_uint(f);
    unsigned int r = (u + 0x7FFFu + ((u >> 16) & 1u)) >> 16;   // RNE
    return (unsigned short)r;
}
__device__ inline float bf16_to_f32(unsigned short h) {
    return __uint_as_float(((unsigned int)h) << 16);
}

// 2 atomics/edge; ticket (returned old count) = slot within the row.
__global__ void k_count(const int* __restrict__ eu, const int* __restrict__ ei,
                        int* __restrict__ cnt,
                        int* __restrict__ tick_u, int* __restrict__ tick_i,
                        int U, int E) {
    int e = blockIdx.x * blockDim.x + threadIdx.x;
    if (e >= E) return;
    int u = eu[e];
    int it = ei[e] + U;
    tick_u[e] = atomicAdd(&cnt[u], 1);
    tick_i[e] = atomicAdd(&cnt[it], 1);
}

// Block scan + one global atomic per block -> disjoint CSR ranges.
__global__ __launch_bounds__(256) void k_offsets(
        const int* __restrict__ cnt, int* __restrict__ offs,
        int* __restrict__ counter, int N) {
    __shared__ int sdata[256];
    __shared__ int sbase;
    int t = threadIdx.x;
    int n = blockIdx.x * 256 + t;
    int c = (n < N) ? cnt[n] : 0;
    sdata[t] = c;
    __syncthreads();
    for (int d = 1; d < 256; d <<= 1) {
        int v = (t >= d) ? sdata[t - d] : 0;
        __syncthreads();
        sdata[t] += v;
        __syncthreads();
    }
    if (t == 255) sbase = atomicAdd(counter, sdata[255]);
    __syncthreads();
    if (n < N) offs[n] = sbase + sdata[t] - c;
}

// Atomic-free scatter: slot = offs[node] + ticket. Stores {col, raw v}.
__global__ void k_scatter(const int* __restrict__ eu, const int* __restrict__ ei,
                          const float* __restrict__ ev,
                          const int* __restrict__ offs,
                          const int* __restrict__ tick_u, const int* __restrict__ tick_i,
                          int2* __restrict__ csr, int U, int E) {
    int e = blockIdx.x * blockDim.x + threadIdx.x;
    if (e >= E) return;
    int u = eu[e];
    int it = ei[e] + U;
    int vy = __float_as_int(ev[e]);
    int2 a;
    a.x = it; a.y = vy;
    csr[offs[u] + tick_u[e]] = a;
    a.x = u;
    csr[offs[it] + tick_i[e]] = a;
}

// One wave per node: deg = sum v over CSR row; dinv = rsqrt(deg), dsq = sqrt(deg).
__global__ __launch_bounds__(256) void k_dinv(
        const int2* __restrict__ csr, const int* __restrict__ offs,
        const int* __restrict__ cnt, float* __restrict__ dinv,
        float* __restrict__ dsq, int N) {
    int gtid = blockIdx.x * blockDim.x + threadIdx.x;
    int wid = gtid >> 6;
    int lane = threadIdx.x & 63;
    if (wid >= N) return;
    int base = offs[wid];
    int c = cnt[wid];
    float s = 0.f;
    for (int k = lane; k < c; k += 64) s += __int_as_float(csr[base + k].y);
    #pragma unroll
    for (int d = 32; d > 0; d >>= 1) s += __shfl_down(s, d);
    if (lane == 0) {
        bool pos = (s > 0.0f);
        dinv[wid] = pos ? rsqrtf(fmaxf(s, 1e-12f)) : 0.0f;
        dsq[wid]  = pos ? sqrtf(s) : 0.0f;
    }
}

// g0 = bf16(dinv * concat(emb)). 4 elems/thread.
__global__ void k_init(const float4* __restrict__ emb_u, const float4* __restrict__ emb_i,
                       const float* __restrict__ dinv,
                       ushort4* __restrict__ g0, int U16, int N16) {
    int i = blockIdx.x * blockDim.x + threadIdx.x;
    if (i >= N16) return;
    float4 v = (i < U16) ? emb_u[i] : emb_i[i - U16];
    float d = dinv[i >> 4];
    ushort4 o;
    o.x = f32_to_bf16(v.x * d);
    o.y = f32_to_bf16(v.y * d);
    o.z = f32_to_bf16(v.z * d);
    o.w = f32_to_bf16(v.w * d);
    g0[i] = o;
}

// One wave per node; lane = dim. Coalesced CSR chunk load + shfl broadcast,
// bf16 gathers (128B/neighbor), 4 accumulators for MLP.
__global__ __launch_bounds__(256) void k_layer(
        const unsigned short* __restrict__ gin, unsigned short* __restrict__ gout,
        const float* __restrict__ dinv,
        const int* __restrict__ offs, const int* __restrict__ cnt,
        const int2* __restrict__ csr, int N) {
    int gtid = blockIdx.x * blockDim.x + threadIdx.x;
    int wid = gtid >> 6;
    int lane = threadIdx.x & 63;
    if (wid >= N) return;
    int base = offs[wid];
    int c = cnt[wid];
    float s0 = 0.f, s1 = 0.f, s2 = 0.f, s3 = 0.f;
    for (int k0 = 0; k0 < c; k0 += 64) {
        int idx = k0 + lane;
        int2 cw = make_int2(0, 0);
        if (idx < c) cw = csr[base + idx];
        int m = min(c - k0, 64);
        int j = 0;
        for (; j + 4 <= m; j += 4) {
            int   c0 = __shfl(cw.x, j);
            int   c1 = __shfl(cw.x, j + 1);
            int   c2 = __shfl(cw.x, j + 2);
            int   c3 = __shfl(cw.x, j + 3);
            float w0 = __int_as_float(__shfl(cw.y, j));
            float w1 = __int_as_float(__shfl(cw.y, j + 1));
            float w2 = __int_as_float(__shfl(cw.y, j + 2));
            float w3 = __int_as_float(__shfl(cw.y, j + 3));
            s0 += w0 * bf16_to_f32(gin[c0 * 64 + lane]);
            s1 += w1 * bf16_to_f32(gin[c1 * 64 + lane]);
            s2 += w2 * bf16_to_f32(gin[c2 * 64 + lane]);
            s3 += w3 * bf16_to_f32(gin[c3 * 64 + lane]);
        }
        for (; j < m; ++j) {
            int   cc = __shfl(cw.x, j);
            float w  = __int_as_float(__shfl(cw.y, j));
            s0 += w * bf16_to_f32(gin[cc * 64 + lane]);
        }
    }
    float dr = dinv[wid];
    float g = dr * dr * ((s0 + s1) + (s2 + s3));   // g' = dinv^2 * s
    gout[wid * 64 + lane] = f32_to_bf16(g);
}

// out (float4 units): [Uf | Upass | If | Ipass]
// Uf/If: (e0 + sum_l dsq*g_l) / 25.
__global__ void k_final(const float4* __restrict__ emb_u, const float4* __restrict__ emb_i,
                        const ushort4* __restrict__ g1, const ushort4* __restrict__ g2,
                        const ushort4* __restrict__ g3, const ushort4* __restrict__ g4,
                        const float* __restrict__ dsq,
                        float4* __restrict__ out, int U16, int I16) {
    int i = blockIdx.x * blockDim.x + threadIdx.x;
    int total = 2 * U16 + 2 * I16;
    if (i >= total) return;
    const float s = 1.0f / 25.0f;
    float4 r;
    if (i < U16 || (i >= 2 * U16 && i < 2 * U16 + I16)) {
        int gi, node;
        float4 e0;
        if (i < U16) { gi = i; node = i >> 4; e0 = emb_u[i]; }
        else { int j = i - 2 * U16; gi = U16 + j; node = (U16 >> 4) + (j >> 4); e0 = emb_i[j]; }
        float d = dsq[node];
        ushort4 a = g1[gi], b = g2[gi], cc = g3[gi], dd = g4[gi];
        float gx = bf16_to_f32(a.x) + bf16_to_f32(b.x) + bf16_to_f32(cc.x) + bf16_to_f32(dd.x);
        float gy = bf16_to_f32(a.y) + bf16_to_f32(b.y) + bf16_to_f32(cc.y) + bf16_to_f32(dd.y);
        float gz = bf16_to_f32(a.z) + bf16_to_f32(b.z) + bf16_to_f32(cc.z) + bf16_to_f32(dd.z);
        float gw = bf16_to_f32(a.w) + bf16_to_f32(b.w) + bf16_to_f32(cc.w) + bf16_to_f32(dd.w);
        r = make_float4((e0.x + d * gx) * s, (e0.y + d * gy) * s,
                        (e0.z + d * gz) * s, (e0.w + d * gw) * s);
    } else if (i < 2 * U16) {
        r = emb_u[i - U16];
    } else {
        r = emb_i[i - 2 * U16 - I16];
    }
    out[i] = r;
}

extern "C" void kernel_launch(void* const* d_in, const int* in_sizes, int n_in,
                              void* d_out, int out_size, void* d_ws, size_t ws_size,
                              hipStream_t stream) {
    const float* emb_u = (const float*)d_in[0];
    const float* emb_i = (const float*)d_in[1];
    const int*   eu    = (const int*)d_in[2];
    const int*   ei    = (const int*)d_in[3];
    const float* ev    = (const float*)d_in[4];

    const int U = in_sizes[0] / 64;
    const int I = in_sizes[1] / 64;
    const int N = U + I;
    const int E = in_sizes[2];
    const int DE = 2 * E;

    // ---- workspace carve ----
    char* base = (char*)d_ws;
    size_t off = 0;
    int*   cnt     = (int*)(base + off); off = align_up(off + (size_t)N * 4, 256);
    int*   counter = (int*)(base + off); off = align_up(off + 256, 256);
    size_t zero_span = off;
    int*   offs   = (int*)  (base + off); off = align_up(off + (size_t)N * 4, 256);
    float* dinv   = (float*)(base + off); off = align_up(off + (size_t)N * 4, 256);
    float* dsq    = (float*)(base + off); off = align_up(off + (size_t)N * 4, 256);
    int*   tick_u = (int*)  (base + off); off = align_up(off + (size_t)E * 4, 256);
    int*   tick_i = (int*)  (base + off); off = align_up(off + (size_t)E * 4, 256);
    int2*  csr    = (int2*) (base + off); off = align_up(off + (size_t)DE * 8, 256);
    unsigned short* g[5];
    for (int l = 0; l < 5; ++l) {
        g[l] = (unsigned short*)(base + off);
        off = align_up(off + (size_t)N * 64 * 2, 256);
    }
    (void)ws_size;

    hipMemsetAsync(d_ws, 0, zero_span, stream);

    const int B = 256;
    k_count<<<(E + B - 1) / B, B, 0, stream>>>(eu, ei, cnt, tick_u, tick_i, U, E);
    k_offsets<<<(N + B - 1) / B, B, 0, stream>>>(cnt, offs, counter, N);
    k_scatter<<<(E + B - 1) / B, B, 0, stream>>>(eu, ei, ev, offs, tick_u, tick_i, csr, U, E);
    k_dinv<<<(N * 64 + B - 1) / B, B, 0, stream>>>(csr, offs, cnt, dinv, dsq, N);

    const int U16 = U * 16, I16 = I * 16, N16 = N * 16;
    k_init<<<(N16 + B - 1) / B, B, 0, stream>>>((const float4*)emb_u, (const float4*)emb_i,
                                                dinv, (ushort4*)g[0], U16, N16);

    for (int layer = 0; layer < 4; ++layer) {
        int threads = N * 64;
        k_layer<<<(threads + B - 1) / B, B, 0, stream>>>(g[layer], g[layer + 1], dinv,
                                                         offs, cnt, csr, N);
    }

    int totalv4 = 2 * U16 + 2 * I16;
    k_final<<<(totalv4 + B - 1) / B, B, 0, stream>>>(
        (const float4*)emb_u, (const float4*)emb_i,
        (const ushort4*)g[1], (const ushort4*)g[2], (const ushort4*)g[3], (const ushort4*)g[4],
        dsq, (float4*)d_out, U16, I16);
}